// Round 3
// baseline (375.073 us; speedup 1.0000x reference)
//
#include <hip/hip_runtime.h>
#include <stdint.h>

// SHEmbed with row-bucketed gather.
// Random (y,x) gather of 192B cells from a 201MB table runs at HBM's random-
// 64B-line rate (~2.3 TB/s, row-activate bound). Fix: bucket rays by y (1024
// buckets, ~192KB table region each), then gather in bucket order -> dense,
// quasi-streaming table sweep + duplicate-cell coalescing in cache.
//
// Pipeline (one stream, fixed order every call; all scratch in d_ws):
//   A zero_counts -> B histogram(y) -> C prefix scan -> D scatter records
//   -> E cooperative gather (4 lanes/ray) + scatter out.
//
// ws layout: [0,64K) counts[1024*16], [64K,128K) cursors[1024*16],
//            [128K, 128K+16M) rec[B] float4(dx,dy,dz,cellbits),
//            [128K+16M, +4M) rayid[B] int.

#define NB   1024
#define PAD  16      // 64B stride per counter -> no same-line atomic pileup

#define SH_C0   0.28209479177387814f
#define SH_C1   0.48860251190291992f
#define SH_C2a  1.09254843059207907f
#define SH_C2b  0.31539156525252005f
#define SH_C2c  0.54627421529603959f
#define SH_C3a  0.59004358992664352f
#define SH_C3b  2.89061144264055405f
#define SH_C3c  0.45704579946446572f
#define SH_C3d  0.37317633259011546f
#define SH_C3e  1.44530572132027702f

#define DO4(v, J0,C0, J1,C1, J2,C2, J3,C3)        \
    s##C0 = fmaf(b[J0], (v).x, s##C0);            \
    s##C1 = fmaf(b[J1], (v).y, s##C1);            \
    s##C2 = fmaf(b[J2], (v).z, s##C2);            \
    s##C3 = fmaf(b[J3], (v).w, s##C3);

__global__ __launch_bounds__(256) void zero_counts(uint32_t* __restrict__ counts, int n)
{
    int i = blockIdx.x * 256 + threadIdx.x;
    if (i < n) counts[i] = 0u;
}

__global__ __launch_bounds__(256) void hist_kernel(
    const int* __restrict__ ys, uint32_t* __restrict__ counts, int B)
{
    __shared__ uint32_t h[NB];
    for (int i = threadIdx.x; i < NB; i += 256) h[i] = 0u;
    __syncthreads();
    int base = blockIdx.x * 4096 + threadIdx.x;
#pragma unroll
    for (int k = 0; k < 16; ++k) {
        int r = base + k * 256;
        if (r < B) atomicAdd(&h[ys[r]], 1u);
    }
    __syncthreads();
    for (int i = threadIdx.x; i < NB; i += 256) {
        uint32_t v = h[i];
        if (v) atomicAdd(&counts[i * PAD], v);
    }
}

__global__ __launch_bounds__(1024) void scan_kernel(
    const uint32_t* __restrict__ counts, uint32_t* __restrict__ cursors)
{
    __shared__ uint32_t t[NB];
    int i = threadIdx.x;
    uint32_t v = counts[i * PAD];
    t[i] = v;
    __syncthreads();
    for (int off = 1; off < NB; off <<= 1) {
        uint32_t add = (i >= off) ? t[i - off] : 0u;
        __syncthreads();
        t[i] += add;
        __syncthreads();
    }
    cursors[i * PAD] = t[i] - v;   // exclusive prefix sum -> bucket cursor
}

__global__ __launch_bounds__(256) void scatter_kernel(
    const int* __restrict__ ys, const int* __restrict__ xs,
    const float* __restrict__ dirs, uint32_t* __restrict__ cursors,
    float4* __restrict__ rec, int* __restrict__ rayid, int B)
{
    int r = blockIdx.x * 256 + threadIdx.x;
    if (r >= B) return;
    int yy = ys[r], xx = xs[r];
    uint32_t pos = atomicAdd(&cursors[yy * PAD], 1u);
    float dx = dirs[3 * r + 0];
    float dy = dirs[3 * r + 1];
    float dz = dirs[3 * r + 2];
    int cell = yy * 1024 + xx;
    rec[pos]   = make_float4(dx, dy, dz, __int_as_float(cell));
    rayid[pos] = r;
}

__global__ __launch_bounds__(256) void gather_kernel(
    const float4* __restrict__ rec, const int* __restrict__ rayid,
    const float* __restrict__ sh, float* __restrict__ out, int B)
{
    int tid  = blockIdx.x * 256 + threadIdx.x;
    int slot = tid >> 2;      // 4 lanes per sorted slot
    int q    = tid & 3;
    if (slot >= B) return;

    float4 rc = rec[slot];                 // broadcast (4 lanes same addr)
    int cell  = __float_as_int(rc.w);
    int ray   = rayid[slot];
    const float4* __restrict__ c4 = (const float4*)(sh + (size_t)cell * 48u);

    // Three 16B loads per lane; quad covers the 192B cell. Dense in bucket order.
    float4 v0 = c4[q];
    float4 v1 = c4[q + 4];
    float4 v2 = c4[q + 8];

    float nxr = rc.x, nyr = rc.y, nzr = rc.z;
    float inv = rsqrtf(fmaf(nxr, nxr, fmaf(nyr, nyr, nzr * nzr)));
    float nx = nxr * inv, ny = nyr * inv, nz = nzr * inv;

    float x2 = nx * nx, y2 = ny * ny, z2 = nz * nz;
    float xy = nx * ny, yz = ny * nz, xz = nx * nz;

    float b[16];
    b[0]  =  SH_C0;
    b[1]  = -SH_C1 * ny;
    b[2]  =  SH_C1 * nz;
    b[3]  = -SH_C1 * nx;
    b[4]  =  SH_C2a * xy;
    b[5]  = -SH_C2a * yz;
    b[6]  =  SH_C2b * (3.0f * z2 - 1.0f);
    b[7]  = -SH_C2a * xz;
    b[8]  =  SH_C2c * (x2 - y2);
    b[9]  = -SH_C3a * ny * (3.0f * x2 - y2);
    b[10] =  SH_C3b * xy * nz;
    b[11] = -SH_C3c * ny * (5.0f * z2 - 1.0f);
    b[12] =  SH_C3d * nz * (5.0f * z2 - 3.0f);
    b[13] = -SH_C3c * nx * (5.0f * z2 - 1.0f);
    b[14] =  SH_C3e * nz * (x2 - y2);
    b[15] = -SH_C3a * nx * (x2 - 3.0f * y2);

    float s0 = 0.0f, s1 = 0.0f, s2 = 0.0f;
    switch (q) {
    case 0:
        DO4(v0,  0,0,  0,1,  0,2,  1,0)
        DO4(v1,  5,1,  5,2,  6,0,  6,1)
        DO4(v2, 10,2, 11,0, 11,1, 11,2)
        break;
    case 1:
        DO4(v0,  1,1,  1,2,  2,0,  2,1)
        DO4(v1,  6,2,  7,0,  7,1,  7,2)
        DO4(v2, 12,0, 12,1, 12,2, 13,0)
        break;
    case 2:
        DO4(v0,  2,2,  3,0,  3,1,  3,2)
        DO4(v1,  8,0,  8,1,  8,2,  9,0)
        DO4(v2, 13,1, 13,2, 14,0, 14,1)
        break;
    default:
        DO4(v0,  4,0,  4,1,  4,2,  5,0)
        DO4(v1,  9,1,  9,2, 10,0, 10,1)
        DO4(v2, 14,2, 15,0, 15,1, 15,2)
        break;
    }

    s0 += __shfl_xor(s0, 1, 64);  s0 += __shfl_xor(s0, 2, 64);
    s1 += __shfl_xor(s1, 1, 64);  s1 += __shfl_xor(s1, 2, 64);
    s2 += __shfl_xor(s2, 1, 64);  s2 += __shfl_xor(s2, 2, 64);

    if (q < 3) {
        float val = (q == 0) ? s0 : (q == 1) ? s1 : s2;
        out[(size_t)3 * ray + q] = fminf(fmaxf(val, 0.0f), 1.0f);
    }
}

extern "C" void kernel_launch(void* const* d_in, const int* in_sizes, int n_in,
                              void* d_out, int out_size, void* d_ws, size_t ws_size,
                              hipStream_t stream) {
    const int*   ys   = (const int*)d_in[0];
    const int*   xs   = (const int*)d_in[1];
    const float* dirs = (const float*)d_in[2];
    const float* sh   = (const float*)d_in[3];
    float* out = (float*)d_out;
    int B = in_sizes[0];

    uint8_t* ws = (uint8_t*)d_ws;
    uint32_t* counts  = (uint32_t*)(ws);                 // 64 KB
    uint32_t* cursors = (uint32_t*)(ws + 65536);         // 64 KB
    float4*   rec     = (float4*)  (ws + 131072);        // 16B-aligned, 16*B bytes
    int*      rayid   = (int*)     (ws + 131072 + (size_t)16 * B);

    // A: zero bucket counters (cursors are fully overwritten by scan).
    zero_counts<<<(NB * PAD + 255) / 256, 256, 0, stream>>>(counts, NB * PAD);
    // B: per-block LDS histogram of y.
    hist_kernel<<<(B + 4095) / 4096, 256, 0, stream>>>(ys, counts, B);
    // C: exclusive prefix scan -> bucket cursors.
    scan_kernel<<<1, 1024, 0, stream>>>(counts, cursors);
    // D: scatter (dir, cell, ray) into bucket-sorted records.
    scatter_kernel<<<(B + 255) / 256, 256, 0, stream>>>(ys, xs, dirs, cursors,
                                                        rec, rayid, B);
    // E: dense cooperative gather in bucket order.
    gather_kernel<<<((B * 4) + 255) / 256, 256, 0, stream>>>(rec, rayid, sh, out, B);
}

// Round 4
// 322.240 us; speedup vs baseline: 1.1640x; 1.1640x over previous
//
#include <hip/hip_runtime.h>
#include <stdint.h>

// SHEmbed R4: L3 warm-up + 4-lane cooperative gather.
// The harness's 805MB ws-poison sweeps the 256MB Infinity Cache each
// iteration, so the 201MB sh_data table is cold and the random 192B-cell
// gather runs at HBM's random-64B-line rate (~2.3 TB/s, row-activate bound).
// Pass 1 streams the table sequentially (~31us) to repopulate the memory-side
// L3; pass 2's random line requests then hit L3 (no row-activate penalty).
// Non-table traffic uses nontemporal ops so it doesn't evict table lines.

#define SH_C0   0.28209479177387814f
#define SH_C1   0.48860251190291992f
#define SH_C2a  1.09254843059207907f
#define SH_C2b  0.31539156525252005f
#define SH_C2c  0.54627421529603959f
#define SH_C3a  0.59004358992664352f
#define SH_C3b  2.89061144264055405f
#define SH_C3c  0.45704579946446572f
#define SH_C3d  0.37317633259011546f
#define SH_C3e  1.44530572132027702f

#define DO4(v, J0,C0, J1,C1, J2,C2, J3,C3)        \
    s##C0 = fmaf(b[J0], (v).x, s##C0);            \
    s##C1 = fmaf(b[J1], (v).y, s##C1);            \
    s##C2 = fmaf(b[J2], (v).z, s##C2);            \
    s##C3 = fmaf(b[J3], (v).w, s##C3);

// Pass 1: stream the whole table into L3. Sum to defeat DCE; write per-thread
// sums into ws (tiny, nontemporal).
__global__ __launch_bounds__(256) void warm_kernel(
    const float4* __restrict__ t, float* __restrict__ sink, int n4)
{
    int tid    = blockIdx.x * 256 + threadIdx.x;
    int stride = gridDim.x * 256;
    float acc = 0.0f;
    for (int i = tid; i < n4; i += stride) {
        float4 v = t[i];
        acc += v.x + v.y + v.z + v.w;
    }
    __builtin_nontemporal_store(acc, sink + tid);
}

__global__ __launch_bounds__(256) void sh_embed_coop(
    const int* __restrict__ ys, const int* __restrict__ xs,
    const float* __restrict__ dirs, const float* __restrict__ sh,
    float* __restrict__ out, int B)
{
    const int tid  = blockIdx.x * 256 + threadIdx.x;
    const int ray  = tid >> 2;          // 4 lanes per ray
    const int q    = tid & 3;           // lane's chunk phase
    if (ray >= B) return;

    // Index loads (4 lanes same address -> broadcast). Nontemporal: don't
    // evict table lines from L3.
    const int yy = __builtin_nontemporal_load(ys + ray);
    const int xx = __builtin_nontemporal_load(xs + ray);
    const float4* __restrict__ c4 =
        (const float4*)(sh + (size_t)(yy * 1024 + xx) * 48u);

    // Three 16B loads per lane; the quad covers the 192B cell (L3-hot).
    const float4 v0 = c4[q];
    const float4 v1 = c4[q + 4];
    const float4 v2 = c4[q + 8];

    const float dx = __builtin_nontemporal_load(dirs + 3 * ray + 0);
    const float dy = __builtin_nontemporal_load(dirs + 3 * ray + 1);
    const float dz = __builtin_nontemporal_load(dirs + 3 * ray + 2);
    const float inv = rsqrtf(fmaf(dx, dx, fmaf(dy, dy, dz * dz)));
    const float nx = dx * inv, ny = dy * inv, nz = dz * inv;

    const float x2 = nx * nx, y2 = ny * ny, z2 = nz * nz;
    const float xy = nx * ny, yz = ny * nz, xz = nx * nz;

    float b[16];
    b[0]  =  SH_C0;
    b[1]  = -SH_C1 * ny;
    b[2]  =  SH_C1 * nz;
    b[3]  = -SH_C1 * nx;
    b[4]  =  SH_C2a * xy;
    b[5]  = -SH_C2a * yz;
    b[6]  =  SH_C2b * (3.0f * z2 - 1.0f);
    b[7]  = -SH_C2a * xz;
    b[8]  =  SH_C2c * (x2 - y2);
    b[9]  = -SH_C3a * ny * (3.0f * x2 - y2);
    b[10] =  SH_C3b * xy * nz;
    b[11] = -SH_C3c * ny * (5.0f * z2 - 1.0f);
    b[12] =  SH_C3d * nz * (5.0f * z2 - 3.0f);
    b[13] = -SH_C3c * nx * (5.0f * z2 - 1.0f);
    b[14] =  SH_C3e * nz * (x2 - y2);
    b[15] = -SH_C3a * nx * (x2 - 3.0f * y2);

    float s0 = 0.0f, s1 = 0.0f, s2 = 0.0f;
    switch (q) {
    case 0:
        DO4(v0,  0,0,  0,1,  0,2,  1,0)
        DO4(v1,  5,1,  5,2,  6,0,  6,1)
        DO4(v2, 10,2, 11,0, 11,1, 11,2)
        break;
    case 1:
        DO4(v0,  1,1,  1,2,  2,0,  2,1)
        DO4(v1,  6,2,  7,0,  7,1,  7,2)
        DO4(v2, 12,0, 12,1, 12,2, 13,0)
        break;
    case 2:
        DO4(v0,  2,2,  3,0,  3,1,  3,2)
        DO4(v1,  8,0,  8,1,  8,2,  9,0)
        DO4(v2, 13,1, 13,2, 14,0, 14,1)
        break;
    default:
        DO4(v0,  4,0,  4,1,  4,2,  5,0)
        DO4(v1,  9,1,  9,2, 10,0, 10,1)
        DO4(v2, 14,2, 15,0, 15,1, 15,2)
        break;
    }

    // Quad butterfly reduction: all 4 lanes end with the full channel sums.
    s0 += __shfl_xor(s0, 1, 64);  s0 += __shfl_xor(s0, 2, 64);
    s1 += __shfl_xor(s1, 1, 64);  s1 += __shfl_xor(s1, 2, 64);
    s2 += __shfl_xor(s2, 1, 64);  s2 += __shfl_xor(s2, 2, 64);

    // Lane 4r+q (q<3) writes out[3*ray+q] -> coalesced 192B per wave.
    if (q < 3) {
        float val = (q == 0) ? s0 : (q == 1) ? s1 : s2;
        val = fminf(fmaxf(val, 0.0f), 1.0f);
        __builtin_nontemporal_store(val, out + (size_t)3 * ray + q);
    }
}

extern "C" void kernel_launch(void* const* d_in, const int* in_sizes, int n_in,
                              void* d_out, int out_size, void* d_ws, size_t ws_size,
                              hipStream_t stream) {
    const int*   ys   = (const int*)d_in[0];
    const int*   xs   = (const int*)d_in[1];
    const float* dirs = (const float*)d_in[2];
    const float* sh   = (const float*)d_in[3];
    float* out = (float*)d_out;
    int B = in_sizes[0];

    // Table = H*W*16*3 floats = 48M floats = 12M float4 = 192MiB.
    const int n4 = in_sizes[3] / 4;
    const int warm_threads = 3072 * 256;          // 16 float4 per thread
    warm_kernel<<<3072, 256, 0, stream>>>((const float4*)sh, (float*)d_ws, n4);

    // 4 threads per ray, 256 threads per block -> 64 rays/block.
    int blocks = (B + 63) / 64;
    sh_embed_coop<<<blocks, 256, 0, stream>>>(ys, xs, dirs, sh, out, B);
    (void)warm_threads; (void)ws_size; (void)out_size; (void)n_in;
}